// Round 9
// baseline (151.680 us; speedup 1.0000x reference)
//
#include <hip/hip_runtime.h>
#include <hip/hip_fp16.h>

// Fused: embedding gather -> masked mean -> ReLU -> linear(20x50)+bias
//   VOCAB=100000, DIM=50, B=4096, L=512, OUT=20
// R7 post-mortem: sharded v1 lost ~6us to its own machinery (int32 bins 9.4MB
// x2, partials 8.4MB x2, marginal 3.8MB/4MB L2 set -> thrash). R8/R9 v2: u16
// bin indices (4.7MB), per-shard zero row ([8][12501] layout), atomicAdd into
// 1MB rep[B][64] (no partials), per-XCD L2 set ~2.3MB << 4MB.
// Decision rule: if this doesn't beat R5's 97.7, sharding is refuted; revert.

#define LMAX     512
#define DIMV     50
#define OUTV     20
#define VOCABSZ  100000
#define NSHARD   8
#define SHROWS   12500      // vocab rows per shard
#define SHSTRIDE 12501      // +1 zero row per shard (sentinel, u16-addressable)
#define BINCAP   576        // 512 tokens + 8 shards * 7 pad max
#define NROWS8   (NSHARD * SHSTRIDE)          // 100008 physical rows
#define TABBLKS  ((NROWS8 * 8 + 255) / 256)   // 8 threads/row -> 3126 blocks

struct __align__(16) H8 { __half2 h[4]; };    // 8 halves = 16 B

// ws layout (256 MiB available; everything read is written first each call):
//   tab  @ 0     : half   [NROWS8][64]   12.80 MB
//   gbin @ 16 MB : ushort [B][BINCAP]     4.72 MB
//   bofs @ 21 MB : int2   [B][NSHARD]     0.26 MB
//   rep  @ 22 MB : float  [B][64]         1.00 MB  (atomicAdd target; prep zeroes)
#define OFF_GBIN (16u << 20)
#define OFF_BOFS (21u << 20)
#define OFF_REP  (22u << 20)

__device__ inline void accum(float4& a0, float4& a1, const H8& h) {
    float2 f0 = __half22float2(h.h[0]);
    float2 f1 = __half22float2(h.h[1]);
    float2 f2 = __half22float2(h.h[2]);
    float2 f3 = __half22float2(h.h[3]);
    a0.x += f0.x; a0.y += f0.y; a0.z += f1.x; a0.w += f1.y;
    a1.x += f2.x; a1.y += f2.y; a1.z += f3.x; a1.w += f3.y;
}

// ---- Kernel 1: table build (blocks < TABBLKS) || binning + rep-zero (one block/sample)
__global__ __launch_bounds__(256) void prep(
    const float* __restrict__ emb, const int* __restrict__ x,
    const int* __restrict__ lengths, char* __restrict__ ws)
{
    const int tid = threadIdx.x;

    if (blockIdx.x < TABBLKS) {
        // f32 -> padded f16 table, sharded layout [8][12501][64] (last row = zeros)
        __half* tab = (__half*)ws;
        const int t  = blockIdx.x * 256 + tid;
        const int r8 = t >> 3, q = t & 7;      // physical row, 8-half chunk
        if (r8 >= NROWS8) return;
        const int s     = r8 / SHSTRIDE;
        const int local = r8 - s * SHSTRIDE;
        float v[8] = {0.f,0.f,0.f,0.f,0.f,0.f,0.f,0.f};
        if (local < SHROWS) {                  // real vocab row (else zero row)
            const int vr = s * SHROWS + local;
            const float* src = emb + vr * DIMV + q * 8;
            if (q < 6) {
                #pragma unroll
                for (int j = 0; j < 8; j += 2) {
                    float2 a = *reinterpret_cast<const float2*>(src + j);
                    v[j] = a.x; v[j + 1] = a.y;
                }
            } else if (q == 6) {               // dims 48,49
                float2 a = *reinterpret_cast<const float2*>(src);
                v[0] = a.x; v[1] = a.y;
            }
        }
        H8 h;
        h.h[0] = __floats2half2_rn(v[0], v[1]);
        h.h[1] = __floats2half2_rn(v[2], v[3]);
        h.h[2] = __floats2half2_rn(v[4], v[5]);
        h.h[3] = __floats2half2_rn(v[6], v[7]);
        *reinterpret_cast<H8*>(tab + r8 * 64 + q * 8) = h;
        return;
    }

    // ---- binning: group sample b's tokens by shard (u16 local rows), pad to x8
    const int b = blockIdx.x - TABBLKS;
    ushort* gbin = (ushort*)(ws + OFF_GBIN);
    int2*   bofs = (int2*)  (ws + OFF_BOFS);
    float*  rep  = (float*) (ws + OFF_REP);

    __shared__ int    sidx[LMAX];
    __shared__ ushort sbin[BINCAP];
    __shared__ int cnt[NSHARD], pcnt[NSHARD], base[NSHARD], pos[NSHARD];

    if (tid < NSHARD) { cnt[tid] = 0; pos[tid] = 0; }
    if (tid < 64) rep[b * 64 + tid] = 0.f;     // zero the atomic target
    __syncthreads();

    const int len = lengths[b];
    #pragma unroll
    for (int i = tid; i < LMAX; i += 256) {
        const int v = x[b * LMAX + i];
        sidx[i] = v;
        if (i < len) atomicAdd(&cnt[v / SHROWS], 1);
    }
    __syncthreads();
    if (tid < NSHARD) {                         // 8-wide exclusive scan (trivial)
        int run = 0;
        for (int j = 0; j < tid; ++j) run += (cnt[j] + 7) & ~7;
        base[tid] = run;
        pcnt[tid] = (cnt[tid] + 7) & ~7;
    }
    __syncthreads();
    #pragma unroll
    for (int i = tid; i < LMAX; i += 256) {
        if (i < len) {
            const int v = sidx[i];
            const int s = v / SHROWS;
            const int p = atomicAdd(&pos[s], 1);   // order irrelevant (sum)
            sbin[base[s] + p] = (ushort)(v - s * SHROWS);
        }
    }
    __syncthreads();
    if (tid < 64) {                             // sentinel-pad: per-shard zero row
        const int s = tid >> 3, k = tid & 7;
        if (cnt[s] + k < pcnt[s]) sbin[base[s] + cnt[s] + k] = (ushort)SHROWS;
    }
    __syncthreads();
    const int total = base[NSHARD - 1] + pcnt[NSHARD - 1];
    for (int j = tid; j < total; j += 256) gbin[b * BINCAP + j] = sbin[j];
    if (tid < NSHARD) bofs[b * NSHARD + tid] = make_int2(base[tid], pcnt[tid]);
}

// ---- Kernel 2: XCD-affine sharded gather. shard = blockIdx&7, wave = sample. ----
__global__ __launch_bounds__(256) void shard_gather(char* __restrict__ ws)
{
    const __half* tab  = (const __half*)ws;
    const ushort* gbin = (const ushort*)(ws + OFF_GBIN);
    const int2*   bofs = (const int2*)  (ws + OFF_BOFS);
    float*        rep  = (float*)       (ws + OFF_REP);

    const int s    = blockIdx.x & 7;            // XCD-affine shard
    const int grp  = blockIdx.x >> 3;
    const int tid  = threadIdx.x;
    const int wave = tid >> 6, lane = tid & 63;
    const int rg   = lane >> 3, cl = lane & 7;  // 8 lanes/row, 8 rows/chunk

    __shared__ ushort slab[4][LMAX];

    const int b  = grp * 4 + wave;
    const int2 of = bofs[b * NSHARD + s];       // .x = base, .y = padded count
    const ushort* seg = gbin + b * BINCAP + of.x;
    for (int i = lane; i < of.y; i += 64) slab[wave][i] = seg[i];
    // slab[wave] is written & read only by this wave -> lgkmcnt ordering suffices.

    const __half* tabs = tab + s * (SHSTRIDE * 64) + cl * 8;
    const int nch = of.y >> 3;
    float4 a0 = {0.f,0.f,0.f,0.f}, a1 = {0.f,0.f,0.f,0.f};
    int c = 0;
    for (; c + 3 < nch; c += 4) {               // 4 x 1KB loads in flight
        const int i0 = slab[wave][(c    ) * 8 + rg];
        const int i1 = slab[wave][(c + 1) * 8 + rg];
        const int i2 = slab[wave][(c + 2) * 8 + rg];
        const int i3 = slab[wave][(c + 3) * 8 + rg];
        H8 h0 = *reinterpret_cast<const H8*>(tabs + (i0 << 6));
        H8 h1 = *reinterpret_cast<const H8*>(tabs + (i1 << 6));
        H8 h2 = *reinterpret_cast<const H8*>(tabs + (i2 << 6));
        H8 h3 = *reinterpret_cast<const H8*>(tabs + (i3 << 6));
        accum(a0, a1, h0); accum(a0, a1, h1);
        accum(a0, a1, h2); accum(a0, a1, h3);
    }
    for (; c < nch; ++c) {
        const int i0 = slab[wave][c * 8 + rg];
        H8 h0 = *reinterpret_cast<const H8*>(tabs + (i0 << 6));
        accum(a0, a1, h0);
    }

    // Butterfly over lane bits 3,4,5: every lane ends with its column's sum
    // (column cl owns dims 8cl..8cl+7).
    #pragma unroll
    for (int m = 8; m <= 32; m <<= 1) {
        a0.x += __shfl_xor(a0.x, m); a0.y += __shfl_xor(a0.y, m);
        a0.z += __shfl_xor(a0.z, m); a0.w += __shfl_xor(a0.w, m);
        a1.x += __shfl_xor(a1.x, m); a1.y += __shfl_xor(a1.y, m);
        a1.z += __shfl_xor(a1.z, m); a1.w += __shfl_xor(a1.w, m);
    }
    if (lane < 8) {                             // lane L: dims 8L..8L+7
        float* p = rep + b * 64 + lane * 8;
        atomicAdd(p + 0, a0.x); atomicAdd(p + 1, a0.y);
        atomicAdd(p + 2, a0.z); atomicAdd(p + 3, a0.w);
        atomicAdd(p + 4, a1.x); atomicAdd(p + 5, a1.y);
        atomicAdd(p + 6, a1.z); atomicAdd(p + 7, a1.w);
    }
}

// ---- Kernel 3: mean -> ReLU -> 20x50 matvec. One wave per sample. ----
__global__ __launch_bounds__(256) void finalize(
    const int* __restrict__ lengths, const float* __restrict__ W,
    const float* __restrict__ bias, const char* __restrict__ ws,
    float* __restrict__ out)
{
    const float* rep = (const float*)(ws + OFF_REP);
    const int tid = threadIdx.x, wave = tid >> 6, lane = tid & 63;
    const int b = blockIdx.x * 4 + wave;

    __shared__ float srep[4][64];

    const float v   = rep[b * 64 + lane];
    const float inv = 1.0f / (float)lengths[b];
    srep[wave][lane] = fmaxf(v * inv, 0.f);     // dims 50..63 are zero
    __syncthreads();

    if (lane < OUTV) {
        float acc = bias[lane];
        const float* wr = W + lane * DIMV;
        #pragma unroll
        for (int d = 0; d < DIMV; ++d) acc += srep[wave][d] * wr[d];
        out[b * OUTV + lane] = acc;
    }
}

extern "C" void kernel_launch(void* const* d_in, const int* in_sizes, int n_in,
                              void* d_out, int out_size, void* d_ws, size_t ws_size,
                              hipStream_t stream) {
    const int*   x       = (const int*)  d_in[0];
    const int*   lengths = (const int*)  d_in[1];
    const float* emb     = (const float*)d_in[2];
    const float* W       = (const float*)d_in[3];
    const float* bias    = (const float*)d_in[4];
    float* out = (float*)d_out;
    char*  ws  = (char*)d_ws;                   // needs 23 MB; ws is 256 MiB

    const int B = in_sizes[1];                  // 4096

    prep<<<TABBLKS + B, 256, 0, stream>>>(emb, x, lengths, ws);
    shard_gather<<<(B / 4) * NSHARD, 256, 0, stream>>>(ws);
    finalize<<<B / 4, 256, 0, stream>>>(lengths, W, bias, ws, out);
}

// Round 10
// 102.699 us; speedup vs baseline: 1.4769x; 1.4769x over previous
//
#include <hip/hip_runtime.h>
#include <hip/hip_fp16.h>

// Fused: embedding gather -> masked mean -> ReLU -> linear(20x50)+bias
//   VOCAB=100000, DIM=50, B=4096, L=512, OUT=20
// R9 post-mortem: XCD sharding CONFIRMED (shard_gather FETCH 95->10 MB) but
// global fp32 atomicAdd partial-sink = 524K fabric RMWs x 128B line writes
// (WRITE 67MB, 66us). R10 v3: same sharded gather, plain coalesced f32
// partials part[B][8][64] (8.4MB stream) + finalize reduce. No atomics.

#define LMAX     512
#define DIMV     50
#define OUTV     20
#define VOCABSZ  100000
#define NSHARD   8
#define SHROWS   12500      // vocab rows per shard
#define SHSTRIDE 12501      // +1 zero row per shard (sentinel, u16-addressable)
#define BINCAP   576        // 512 tokens + 8 shards * 7 pad max
#define NROWS8   (NSHARD * SHSTRIDE)          // 100008 physical rows
#define TABBLKS  ((NROWS8 * 8 + 255) / 256)   // 8 threads/row -> 3126 blocks

struct __align__(16) H8 { __half2 h[4]; };    // 8 halves = 16 B

// ws layout (256 MiB available; everything read is written first each call):
//   tab  @ 0     : half   [NROWS8][64]       12.80 MB
//   gbin @ 16 MB : ushort [B][BINCAP]         4.72 MB
//   bofs @ 21 MB : int2   [B][NSHARD]         0.26 MB
//   part @ 22 MB : float  [B][NSHARD][64]     8.39 MB
#define OFF_GBIN (16u << 20)
#define OFF_BOFS (21u << 20)
#define OFF_PART (22u << 20)

__device__ inline void accum(float4& a0, float4& a1, const H8& h) {
    float2 f0 = __half22float2(h.h[0]);
    float2 f1 = __half22float2(h.h[1]);
    float2 f2 = __half22float2(h.h[2]);
    float2 f3 = __half22float2(h.h[3]);
    a0.x += f0.x; a0.y += f0.y; a0.z += f1.x; a0.w += f1.y;
    a1.x += f2.x; a1.y += f2.y; a1.z += f3.x; a1.w += f3.y;
}

// ---- Kernel 1: table build (blocks < TABBLKS) || binning (one block/sample) ----
__global__ __launch_bounds__(256) void prep(
    const float* __restrict__ emb, const int* __restrict__ x,
    const int* __restrict__ lengths, char* __restrict__ ws)
{
    const int tid = threadIdx.x;

    if (blockIdx.x < TABBLKS) {
        // f32 -> padded f16 table, sharded layout [8][12501][64] (last row = zeros)
        __half* tab = (__half*)ws;
        const int t  = blockIdx.x * 256 + tid;
        const int r8 = t >> 3, q = t & 7;      // physical row, 8-half chunk
        if (r8 >= NROWS8) return;
        const int s     = r8 / SHSTRIDE;
        const int local = r8 - s * SHSTRIDE;
        float v[8] = {0.f,0.f,0.f,0.f,0.f,0.f,0.f,0.f};
        if (local < SHROWS) {                  // real vocab row (else zero row)
            const int vr = s * SHROWS + local;
            const float* src = emb + vr * DIMV + q * 8;
            if (q < 6) {
                #pragma unroll
                for (int j = 0; j < 8; j += 2) {
                    float2 a = *reinterpret_cast<const float2*>(src + j);
                    v[j] = a.x; v[j + 1] = a.y;
                }
            } else if (q == 6) {               // dims 48,49
                float2 a = *reinterpret_cast<const float2*>(src);
                v[0] = a.x; v[1] = a.y;
            }
        }
        H8 h;
        h.h[0] = __floats2half2_rn(v[0], v[1]);
        h.h[1] = __floats2half2_rn(v[2], v[3]);
        h.h[2] = __floats2half2_rn(v[4], v[5]);
        h.h[3] = __floats2half2_rn(v[6], v[7]);
        *reinterpret_cast<H8*>(tab + r8 * 64 + q * 8) = h;
        return;
    }

    // ---- binning: group sample b's tokens by shard (u16 local rows), pad to x8
    const int b = blockIdx.x - TABBLKS;
    ushort* gbin = (ushort*)(ws + OFF_GBIN);
    int2*   bofs = (int2*)  (ws + OFF_BOFS);

    __shared__ int    sidx[LMAX];
    __shared__ ushort sbin[BINCAP];
    __shared__ int cnt[NSHARD], pcnt[NSHARD], base[NSHARD], pos[NSHARD];

    if (tid < NSHARD) { cnt[tid] = 0; pos[tid] = 0; }
    __syncthreads();

    const int len = lengths[b];
    #pragma unroll
    for (int i = tid; i < LMAX; i += 256) {
        const int v = x[b * LMAX + i];
        sidx[i] = v;
        if (i < len) atomicAdd(&cnt[v / SHROWS], 1);   // LDS atomics: cheap
    }
    __syncthreads();
    if (tid < NSHARD) {                         // 8-wide exclusive scan (trivial)
        int run = 0;
        for (int j = 0; j < tid; ++j) run += (cnt[j] + 7) & ~7;
        base[tid] = run;
        pcnt[tid] = (cnt[tid] + 7) & ~7;
    }
    __syncthreads();
    #pragma unroll
    for (int i = tid; i < LMAX; i += 256) {
        if (i < len) {
            const int v = sidx[i];
            const int s = v / SHROWS;
            const int p = atomicAdd(&pos[s], 1);   // order irrelevant (sum)
            sbin[base[s] + p] = (ushort)(v - s * SHROWS);
        }
    }
    __syncthreads();
    if (tid < 64) {                             // sentinel-pad: per-shard zero row
        const int s = tid >> 3, k = tid & 7;
        if (cnt[s] + k < pcnt[s]) sbin[base[s] + cnt[s] + k] = (ushort)SHROWS;
    }
    __syncthreads();
    const int total = base[NSHARD - 1] + pcnt[NSHARD - 1];
    for (int j = tid; j < total; j += 256) gbin[b * BINCAP + j] = sbin[j];
    if (tid < NSHARD) bofs[b * NSHARD + tid] = make_int2(base[tid], pcnt[tid]);
}

// ---- Kernel 2: XCD-affine sharded gather. shard = blockIdx&7, wave = sample. ----
__global__ __launch_bounds__(256) void shard_gather(char* __restrict__ ws)
{
    const __half* tab  = (const __half*)ws;
    const ushort* gbin = (const ushort*)(ws + OFF_GBIN);
    const int2*   bofs = (const int2*)  (ws + OFF_BOFS);
    float*        part = (float*)       (ws + OFF_PART);

    const int s    = blockIdx.x & 7;            // XCD-affine shard
    const int grp  = blockIdx.x >> 3;
    const int tid  = threadIdx.x;
    const int wave = tid >> 6, lane = tid & 63;
    const int rg   = lane >> 3, cl = lane & 7;  // 8 lanes/row, 8 rows/chunk

    __shared__ ushort slab[4][LMAX];

    const int b  = grp * 4 + wave;
    const int2 of = bofs[b * NSHARD + s];       // .x = base, .y = padded count
    const ushort* seg = gbin + b * BINCAP + of.x;
    for (int i = lane; i < of.y; i += 64) slab[wave][i] = seg[i];
    // slab[wave] written & read only by this wave -> lgkmcnt ordering suffices.

    const __half* tabs = tab + s * (SHSTRIDE * 64) + cl * 8;
    const int nch = of.y >> 3;
    float4 a0 = {0.f,0.f,0.f,0.f}, a1 = {0.f,0.f,0.f,0.f};
    int c = 0;
    for (; c + 3 < nch; c += 4) {               // 4 x 1KB loads in flight
        const int i0 = slab[wave][(c    ) * 8 + rg];
        const int i1 = slab[wave][(c + 1) * 8 + rg];
        const int i2 = slab[wave][(c + 2) * 8 + rg];
        const int i3 = slab[wave][(c + 3) * 8 + rg];
        H8 h0 = *reinterpret_cast<const H8*>(tabs + (i0 << 6));
        H8 h1 = *reinterpret_cast<const H8*>(tabs + (i1 << 6));
        H8 h2 = *reinterpret_cast<const H8*>(tabs + (i2 << 6));
        H8 h3 = *reinterpret_cast<const H8*>(tabs + (i3 << 6));
        accum(a0, a1, h0); accum(a0, a1, h1);
        accum(a0, a1, h2); accum(a0, a1, h3);
    }
    for (; c < nch; ++c) {
        const int i0 = slab[wave][c * 8 + rg];
        H8 h0 = *reinterpret_cast<const H8*>(tabs + (i0 << 6));
        accum(a0, a1, h0);
    }

    // Butterfly over lane bits 3,4,5: every lane ends with its column's sum
    // (column cl owns dims 8cl..8cl+7).
    #pragma unroll
    for (int m = 8; m <= 32; m <<= 1) {
        a0.x += __shfl_xor(a0.x, m); a0.y += __shfl_xor(a0.y, m);
        a0.z += __shfl_xor(a0.z, m); a0.w += __shfl_xor(a0.w, m);
        a1.x += __shfl_xor(a1.x, m); a1.y += __shfl_xor(a1.y, m);
        a1.z += __shfl_xor(a1.z, m); a1.w += __shfl_xor(a1.w, m);
    }
    if (lane < 8) {                             // plain coalesced stores, no atomics
        float* p = part + ((b * NSHARD) + s) * 64 + lane * 8;
        *reinterpret_cast<float4*>(p)     = a0;
        *reinterpret_cast<float4*>(p + 4) = a1;
    }
}

// ---- Kernel 3: reduce 8 partials -> mean -> ReLU -> 20x50 matvec ----
__global__ __launch_bounds__(256) void finalize(
    const int* __restrict__ lengths, const float* __restrict__ W,
    const float* __restrict__ bias, const char* __restrict__ ws,
    float* __restrict__ out)
{
    const float* part = (const float*)(ws + OFF_PART);
    const int tid = threadIdx.x, wave = tid >> 6, lane = tid & 63;
    const int b = blockIdx.x * 4 + wave;

    __shared__ float srep[4][64];

    float v = 0.f;
    #pragma unroll
    for (int s = 0; s < NSHARD; ++s)
        v += part[((b * NSHARD) + s) * 64 + lane];   // coalesced per s
    const float inv = 1.0f / (float)lengths[b];
    srep[wave][lane] = fmaxf(v * inv, 0.f);          // dims 50..63 are zero
    __syncthreads();

    if (lane < OUTV) {
        float acc = bias[lane];
        const float* wr = W + lane * DIMV;
        #pragma unroll
        for (int d = 0; d < DIMV; ++d) acc += srep[wave][d] * wr[d];
        out[b * OUTV + lane] = acc;
    }
}

extern "C" void kernel_launch(void* const* d_in, const int* in_sizes, int n_in,
                              void* d_out, int out_size, void* d_ws, size_t ws_size,
                              hipStream_t stream) {
    const int*   x       = (const int*)  d_in[0];
    const int*   lengths = (const int*)  d_in[1];
    const float* emb     = (const float*)d_in[2];
    const float* W       = (const float*)d_in[3];
    const float* bias    = (const float*)d_in[4];
    float* out = (float*)d_out;
    char*  ws  = (char*)d_ws;                   // needs ~31 MB; ws is 256 MiB

    const int B = in_sizes[1];                  // 4096

    prep<<<TABBLKS + B, 256, 0, stream>>>(emb, x, lengths, ws);
    shard_gather<<<(B / 4) * NSHARD, 256, 0, stream>>>(ws);
    finalize<<<B / 4, 256, 0, stream>>>(lengths, W, bias, ws, out);
}

// Round 11
// 97.522 us; speedup vs baseline: 1.5553x; 1.0531x over previous
//
#include <hip/hip_runtime.h>
#include <hip/hip_fp16.h>

// Fused: embedding gather -> masked mean -> ReLU -> linear(20x50)+bias
//   VOCAB=100000, DIM=50, B=4096, L=512, OUT=20
// FINAL (revert to R5, best measured 97.7us):
//  - R2: f32 gather 130MB fetch @ ~3TB/s -> 44us. f16 table halves miss bytes.
//  - R4/R5: padded 128B f16 rows, 8 tokens/wave-instruction, branch-free via
//    zero-row sentinel -> gather ~23us, FETCH ~95MB = compulsory (8 XCDs x
//    12.8MB table through 4MB L2s). Width-doubling null -> fabric-rate-bound.
//  - R9: XCD sharding proved L2-resident gather (FETCH 10MB) but its machinery
//    (binning + partials, R7/R10) costs more than the 13us it saves; global
//    f32 atomics are 128B/RMW fabric write-through (66us). Refuted; reverted.

#define LMAX    512
#define DIMV    50
#define OUTV    20
#define VOCABSZ 100000
#define RSTRIDE 64     // padded row stride in halves (128 B)

struct __align__(16) H8 { __half2 h[4]; };   // 8 halves = 16 B

// ---- Kernel 1: build padded f16 table in ws (+1 zero row at index VOCABSZ) ----
// thread t: row r = t>>3, chunk q = t&7 -> halves 8q..8q+7 (dims >=50 zero).
__global__ __launch_bounds__(256) void build_tab(
    const float* __restrict__ emb, __half* __restrict__ tab)
{
    const int t = blockIdx.x * 256 + threadIdx.x;
    const int r = t >> 3;
    const int q = t & 7;
    if (r > VOCABSZ) return;
    float v[8] = {0.f, 0.f, 0.f, 0.f, 0.f, 0.f, 0.f, 0.f};
    if (r < VOCABSZ) {
        const float* src = emb + r * DIMV + q * 8;   // 8B-aligned (200B rows)
        if (q < 6) {
            #pragma unroll
            for (int j = 0; j < 8; j += 2) {
                float2 a = *reinterpret_cast<const float2*>(src + j);
                v[j] = a.x; v[j + 1] = a.y;
            }
        } else if (q == 6) {                         // dims 48,49
            float2 a = *reinterpret_cast<const float2*>(src);
            v[0] = a.x; v[1] = a.y;
        }
    }
    H8 h;
    h.h[0] = __floats2half2_rn(v[0], v[1]);
    h.h[1] = __floats2half2_rn(v[2], v[3]);
    h.h[2] = __floats2half2_rn(v[4], v[5]);
    h.h[3] = __floats2half2_rn(v[6], v[7]);
    *reinterpret_cast<H8*>(tab + r * RSTRIDE + q * 8) = h;
}

__device__ inline void accum(float4& a0, float4& a1, const H8& h) {
    float2 f0 = __half22float2(h.h[0]);
    float2 f1 = __half22float2(h.h[1]);
    float2 f2 = __half22float2(h.h[2]);
    float2 f3 = __half22float2(h.h[3]);
    a0.x += f0.x; a0.y += f0.y; a0.z += f1.x; a0.w += f1.y;
    a1.x += f2.x; a1.y += f2.y; a1.z += f3.x; a1.w += f3.y;
}

// ---- Kernel 2: fused gather/mean/relu/linear. One block per sample. ----
// lane = 8*rg + cl: row-group rg in [0,8) (token-in-chunk), column cl in [0,8)
// (8 halves each). One load instruction = 8 tokens x 128 B = 1 KB coalesced.
__global__ __launch_bounds__(256) void fused_gather(
    const int*    __restrict__ x,
    const int*    __restrict__ lengths,
    const __half* __restrict__ tab,
    const float*  __restrict__ W,
    const float*  __restrict__ bias,
    float*        __restrict__ out)
{
    const int b    = blockIdx.x;
    const int tid  = threadIdx.x;
    const int wave = tid >> 6;
    const int lane = tid & 63;
    const int rg   = lane >> 3;     // which row of the 8-token chunk
    const int cl   = lane & 7;      // 8-half column within row

    __shared__ int   sidx[LMAX];
    __shared__ float sacc[4][64];
    __shared__ float srep[DIMV];

    const int len = lengths[b];

    // Stage all 512 indices; tokens >= len point at the zero row (branch-free hot loop).
    const int xbase = b * LMAX;
    #pragma unroll
    for (int i = 0; i < LMAX; i += 256) {
        const int ii = i + tid;
        const int v  = x[xbase + ii];
        sidx[ii] = (ii < len) ? v : VOCABSZ;
    }
    __syncthreads();

    const __half* tabc = tab + cl * 8;       // lane-constant column base (16B-aligned)
    const int nchunk = (len + 7) >> 3;       // 8-token chunks (max 64)
    float4 a0 = {0.f, 0.f, 0.f, 0.f};
    float4 a1 = {0.f, 0.f, 0.f, 0.f};

    int c = wave;
    // 8 chunks (64 tokens, 8 x 1KB loads) in flight per wave.
    for (; c + 28 < nchunk; c += 32) {
        int i0 = sidx[(c     ) * 8 + rg];
        int i1 = sidx[(c +  4) * 8 + rg];
        int i2 = sidx[(c +  8) * 8 + rg];
        int i3 = sidx[(c + 12) * 8 + rg];
        int i4 = sidx[(c + 16) * 8 + rg];
        int i5 = sidx[(c + 20) * 8 + rg];
        int i6 = sidx[(c + 24) * 8 + rg];
        int i7 = sidx[(c + 28) * 8 + rg];
        H8 h0 = *reinterpret_cast<const H8*>(tabc + (i0 << 6));
        H8 h1 = *reinterpret_cast<const H8*>(tabc + (i1 << 6));
        H8 h2 = *reinterpret_cast<const H8*>(tabc + (i2 << 6));
        H8 h3 = *reinterpret_cast<const H8*>(tabc + (i3 << 6));
        H8 h4 = *reinterpret_cast<const H8*>(tabc + (i4 << 6));
        H8 h5 = *reinterpret_cast<const H8*>(tabc + (i5 << 6));
        H8 h6 = *reinterpret_cast<const H8*>(tabc + (i6 << 6));
        H8 h7 = *reinterpret_cast<const H8*>(tabc + (i7 << 6));
        accum(a0, a1, h0); accum(a0, a1, h1); accum(a0, a1, h2); accum(a0, a1, h3);
        accum(a0, a1, h4); accum(a0, a1, h5); accum(a0, a1, h6); accum(a0, a1, h7);
    }
    for (; c < nchunk; c += 4) {
        int i0 = sidx[c * 8 + rg];
        H8 h0 = *reinterpret_cast<const H8*>(tabc + (i0 << 6));
        accum(a0, a1, h0);
    }

    // Sum the 8 row-groups (butterfly over lane bits 3,4,5). Lanes 0-7 hold result.
    #pragma unroll
    for (int m = 8; m <= 32; m <<= 1) {
        a0.x += __shfl_xor(a0.x, m); a0.y += __shfl_xor(a0.y, m);
        a0.z += __shfl_xor(a0.z, m); a0.w += __shfl_xor(a0.w, m);
        a1.x += __shfl_xor(a1.x, m); a1.y += __shfl_xor(a1.y, m);
        a1.z += __shfl_xor(a1.z, m); a1.w += __shfl_xor(a1.w, m);
    }
    if (lane < 8) {
        *reinterpret_cast<float4*>(&sacc[wave][lane * 8])     = a0;
        *reinterpret_cast<float4*>(&sacc[wave][lane * 8 + 4]) = a1;
    }
    __syncthreads();

    // Cross-wave reduce + mean + ReLU (dims 50..63 are zero-padding, ignored).
    if (tid < DIMV) {
        float s = sacc[0][tid] + sacc[1][tid] + sacc[2][tid] + sacc[3][tid];
        srep[tid] = fmaxf(s / (float)len, 0.f);
    }
    __syncthreads();

    // Tiny matvec: 20 outputs x 50-dot (W is 4KB, cache-resident).
    if (tid < OUTV) {
        float s = bias[tid];
        const float* wr = W + tid * DIMV;
        #pragma unroll
        for (int d = 0; d < DIMV; ++d) s += srep[d] * wr[d];
        out[b * OUTV + tid] = s;
    }
}

extern "C" void kernel_launch(void* const* d_in, const int* in_sizes, int n_in,
                              void* d_out, int out_size, void* d_ws, size_t ws_size,
                              hipStream_t stream) {
    const int*   x       = (const int*)  d_in[0];
    const int*   lengths = (const int*)  d_in[1];
    const float* emb     = (const float*)d_in[2];
    const float* W       = (const float*)d_in[3];
    const float* bias    = (const float*)d_in[4];
    float*  out = (float*)d_out;
    __half* tab = (__half*)d_ws;    // (VOCAB+1) x 64 halves = 12.8 MB

    const int B = in_sizes[1];      // 4096

    const int nthr = (VOCABSZ + 1) * 8;
    build_tab<<<(nthr + 255) / 256, 256, 0, stream>>>(emb, tab);
    fused_gather<<<B, 256, 0, stream>>>(x, lengths, tab, W, bias, out);
}